// Round 5
// baseline (45.788 us; speedup 1.0000x reference)
//
#include <hip/hip_runtime.h>

constexpr int KWIN = 100;
constexpr int HK   = 50;
constexpr int TSUB = 64;    // frames per thread
constexpr int MB   = 8;     // incoming loads batched per inner block
constexpr int PB   = 10;    // prime batch

__global__ __launch_bounds__(256, 4) void man_kernel(
    const float* __restrict__ x, float* __restrict__ out)
{
    constexpr int T = 16384, D = 128;

    const int i     = blockIdx.x;                 // 0..1023
    const int bb    = (i & 7) * 128 + (i >> 3);   // XCD (i&7) owns batch b
    const int b     = bb >> 7;                    // 0..7
    const int cpair = bb & 127;                   // pair of adjacent chunks
    const int w     = threadIdx.x >> 7;           // 0..1 chunk within pair
    const int tid   = threadIdx.x & 127;          // d column
    const int t0    = (cpair * 2 + w) * TSUB;

    const float* __restrict__ xb = x   + (size_t)b * T * D + tid;
    float*       __restrict__ ob = out + (size_t)b * T * D + tid;

    auto ridx = [](int t) -> int {                // reflect, branchless
        t = (t < 0) ? -t : t;
        return (t >= T) ? (2 * T - 2 - t) : t;
    };

    // 100-slot ring entirely in registers; all indices compile-time static.
    float v[KWIN];
    float sx = 0.f, sq = 0.f;

    // ---- prime: frames t0-50 .. t0+49 -> v[0..99] ----
    #pragma unroll
    for (int jb = 0; jb < KWIN; jb += PB) {
        float g[PB];
        #pragma unroll
        for (int j = 0; j < PB; ++j)
            g[j] = xb[(size_t)ridx(t0 - HK + jb + j) * D];
        #pragma unroll
        for (int j = 0; j < PB; ++j) {
            v[jb + j] = g[j];
            sx += g[j];
            sq  = fmaf(g[j], g[j], sq);
        }
    }

    const float invK   = 1.0f / (float)KWIN;
    const float invKm1 = 1.0f / (float)(KWIN - 1);
    const float fK     = (float)KWIN;

    // ---- main: 64 outputs, fully unrolled; ring slot jj%100 static ----
    #pragma unroll
    for (int tb = 0; tb < TSUB; tb += MB) {
        float g[MB];
        #pragma unroll
        for (int j = 0; j < MB; ++j)
            g[j] = xb[(size_t)ridx(t0 + tb + j + HK) * D];  // incoming x[t+50]
        #pragma unroll
        for (int j = 0; j < MB; ++j) {
            const int jj = tb + j;
            const float c = v[(jj + HK) % KWIN];  // center x[t]
            const float o = v[jj % KWIN];         // outgoing x[t-50]
            const float m  = sx * invK;
            float va = fmaxf((sq - fK * m * m) * invKm1, 1e-24f);
            const float rs = __builtin_amdgcn_rsqf(va);   // v_rsq_f32
            ob[(size_t)(t0 + jj) * D] = (c - m) * rs;
            sx += g[j] - o;
            sq += g[j] * g[j] - o * o;
            v[jj % KWIN] = g[j];                  // refill freed slot
        }
    }
}

extern "C" void kernel_launch(void* const* d_in, const int* in_sizes, int n_in,
                              void* d_out, int out_size, void* d_ws, size_t ws_size,
                              hipStream_t stream) {
    (void)in_sizes; (void)n_in; (void)d_ws; (void)ws_size; (void)out_size;
    const float* x = (const float*)d_in[0];
    float* out = (float*)d_out;
    // 8 b * 256 chunks * 128 d = 262144 threads = 1024 blocks * 256
    man_kernel<<<dim3(1024), dim3(256), 0, stream>>>(x, out);
}

// Round 6
// 33.873 us; speedup vs baseline: 1.3517x; 1.3517x over previous
//
#include <hip/hip_runtime.h>

constexpr int KWIN = 100;
constexpr int HK   = 50;
constexpr int TSUB = 64;    // frames per thread
constexpr int MB   = 8;     // incoming loads batched per inner block
constexpr int PB   = 10;    // prime batch

template <bool REFLECT>
__device__ __forceinline__ int tidx(int t) {
    if constexpr (REFLECT) {
        constexpr int T = 16384;
        t = (t < 0) ? -t : t;
        return (t >= T) ? (2 * T - 2 - t) : t;
    } else {
        return t;   // interior chunk: linear addressing, imm-offset friendly
    }
}

template <bool REFLECT>
__device__ __forceinline__ void run_chunk(
    const float* __restrict__ xb, float* __restrict__ ob, const int t0)
{
    constexpr int D = 128;

    // 100-slot ring entirely in registers; every index below is a
    // compile-time constant (loops fully unrolled) -> no scratch.
    float v[KWIN];
    float sx = 0.f, sq = 0.f;

    // ---- prime: frames t0-50 .. t0+49 -> v[0..99] ----
    #pragma unroll
    for (int jb = 0; jb < KWIN; jb += PB) {
        float g[PB];
        #pragma unroll
        for (int j = 0; j < PB; ++j)
            g[j] = xb[(size_t)tidx<REFLECT>(t0 - HK + jb + j) * D];
        #pragma unroll
        for (int j = 0; j < PB; ++j) {
            v[jb + j] = g[j];
            sx += g[j];
            sq  = fmaf(g[j], g[j], sq);
        }
    }

    const float invK   = 1.0f / (float)KWIN;
    const float invKm1 = 1.0f / (float)(KWIN - 1);
    const float fK     = (float)KWIN;

    // ---- main: 64 outputs, fully unrolled; ring slot jj%100 static ----
    #pragma unroll
    for (int tb = 0; tb < TSUB; tb += MB) {
        float g[MB];
        #pragma unroll
        for (int j = 0; j < MB; ++j)
            g[j] = xb[(size_t)tidx<REFLECT>(t0 + tb + j + HK) * D];
        #pragma unroll
        for (int j = 0; j < MB; ++j) {
            const int jj = tb + j;
            const float c = v[(jj + HK) % KWIN];   // center x[t]
            const float o = v[jj % KWIN];          // outgoing x[t-50]
            const float m  = sx * invK;
            const float va = fmaxf((sq - fK * m * m) * invKm1, 1e-24f);
            const float rs = __builtin_amdgcn_rsqf(va);   // v_rsq_f32
            ob[(size_t)(t0 + jj) * D] = (c - m) * rs;
            sx += g[j] - o;
            sq += g[j] * g[j] - o * o;
            v[jj % KWIN] = g[j];                   // refill freed slot
        }
    }
}

__global__ __launch_bounds__(256, 2) void man_kernel(
    const float* __restrict__ x, float* __restrict__ out)
{
    constexpr int T = 16384, D = 128;

    const int i     = blockIdx.x;                 // 0..1023
    const int bb    = (i & 7) * 128 + (i >> 3);   // XCD (i&7) owns batch b
    const int b     = bb >> 7;                    // 0..7
    const int cpair = bb & 127;                   // pair of adjacent chunks
    const int w     = threadIdx.x >> 7;           // 0..1 chunk within pair
    const int tid   = threadIdx.x & 127;          // d column
    const int t0    = (cpair * 2 + w) * TSUB;

    const float* __restrict__ xb = x   + (size_t)b * T * D + tid;
    float*       __restrict__ ob = out + (size_t)b * T * D + tid;

    // Only chunk 0 (t0-50 < 0) and the last chunk (t0+63+50 >= T) reflect.
    if (t0 >= HK && t0 + TSUB - 1 + HK < T) {
        run_chunk<false>(xb, ob, t0);
    } else {
        run_chunk<true>(xb, ob, t0);
    }
}

extern "C" void kernel_launch(void* const* d_in, const int* in_sizes, int n_in,
                              void* d_out, int out_size, void* d_ws, size_t ws_size,
                              hipStream_t stream) {
    (void)in_sizes; (void)n_in; (void)d_ws; (void)ws_size; (void)out_size;
    const float* x = (const float*)d_in[0];
    float* out = (float*)d_out;
    // 8 b * 256 chunks * 128 d = 262144 threads = 1024 blocks * 256
    man_kernel<<<dim3(1024), dim3(256), 0, stream>>>(x, out);
}

// Round 7
// 31.755 us; speedup vs baseline: 1.4419x; 1.0667x over previous
//
#include <hip/hip_runtime.h>

constexpr int KWIN = 100;
constexpr int HK   = 50;
constexpr int TSUB = 32;    // frames per thread
constexpr int MB   = 8;     // outputs per inner batch (24 loads in flight)
constexpr int PB   = 20;    // prime batch (20 loads in flight)

template <bool REFLECT>
__device__ __forceinline__ int tidx(int t) {
    if constexpr (REFLECT) {
        constexpr int T = 16384;
        t = (t < 0) ? -t : t;
        return (t >= T) ? (2 * T - 2 - t) : t;
    }
    return t;   // interior chunk: linear addressing
}

template <bool REFLECT>
__device__ __forceinline__ void run_chunk(
    const float* __restrict__ xb, float* __restrict__ ob, const int t0)
{
    constexpr int D = 128;

    float sx = 0.f, sq = 0.f;

    // ---- prime: window [t0-50, t0+49], 5 batches of 20 loads ----
    #pragma unroll
    for (int jb = 0; jb < KWIN; jb += PB) {
        float g[PB];
        #pragma unroll
        for (int j = 0; j < PB; ++j)
            g[j] = xb[(size_t)tidx<REFLECT>(t0 - HK + jb + j) * D];
        #pragma unroll
        for (int j = 0; j < PB; ++j) {
            sx += g[j];
            sq  = fmaf(g[j], g[j], sq);
        }
    }

    const float invK   = 1.0f / (float)KWIN;
    const float invKm1 = 1.0f / (float)(KWIN - 1);
    const float fK     = (float)KWIN;

    // ---- main: 32 outputs; per batch issue 24 independent loads ----
    #pragma unroll
    for (int tb = 0; tb < TSUB; tb += MB) {
        float c[MB], o[MB], g[MB];
        #pragma unroll
        for (int j = 0; j < MB; ++j) {
            const int t = t0 + tb + j;
            c[j] = xb[(size_t)t * D];                        // x[t]: never reflects
            o[j] = xb[(size_t)tidx<REFLECT>(t - HK) * D];    // x[t-50]
            g[j] = xb[(size_t)tidx<REFLECT>(t + HK) * D];    // x[t+50]
        }
        #pragma unroll
        for (int j = 0; j < MB; ++j) {
            const float m  = sx * invK;
            const float va = fmaxf((sq - fK * m * m) * invKm1, 1e-24f);
            const float rs = __builtin_amdgcn_rsqf(va);      // v_rsq_f32
            ob[(size_t)(t0 + tb + j) * D] = (c[j] - m) * rs;
            sx += g[j] - o[j];
            sq += g[j] * g[j] - o[j] * o[j];
        }
    }
}

__global__ __launch_bounds__(256, 2) void man_kernel(
    const float* __restrict__ x, float* __restrict__ out)
{
    constexpr int T = 16384, D = 128;

    const int i    = blockIdx.x;                  // 0..2047
    const int bb   = (i & 7) * 256 + (i >> 3);    // XCD (i&7) owns batch b
    const int b    = bb >> 8;                     // 0..7
    const int pair = bb & 255;                    // pair of adjacent chunks
    const int w    = threadIdx.x >> 7;            // 0..1 chunk within pair
    const int tid  = threadIdx.x & 127;           // d column
    const int t0   = (pair * 2 + w) * TSUB;

    const float* __restrict__ xb = x   + (size_t)b * T * D + tid;
    float*       __restrict__ ob = out + (size_t)b * T * D + tid;

    if (t0 >= HK && t0 + TSUB - 1 + HK < T) {
        run_chunk<false>(xb, ob, t0);
    } else {
        run_chunk<true>(xb, ob, t0);
    }
}

extern "C" void kernel_launch(void* const* d_in, const int* in_sizes, int n_in,
                              void* d_out, int out_size, void* d_ws, size_t ws_size,
                              hipStream_t stream) {
    (void)in_sizes; (void)n_in; (void)d_ws; (void)ws_size; (void)out_size;
    const float* x = (const float*)d_in[0];
    float* out = (float*)d_out;
    // 8 b * 512 chunks * 128 d = 524288 threads = 2048 blocks * 256
    man_kernel<<<dim3(2048), dim3(256), 0, stream>>>(x, out);
}